// Round 6
// baseline (162.961 us; speedup 1.0000x reference)
//
#include <hip/hip_runtime.h>
#include <cstdint>
#include <cstddef>

#define D 64

typedef float    f32x4 __attribute__((ext_vector_type(4)));
typedef short    s16x8 __attribute__((ext_vector_type(8)));
typedef uint32_t u32x4 __attribute__((ext_vector_type(4)));

// round-to-nearest-even fp32 -> bf16 (bits in low 16)
__device__ __forceinline__ uint32_t rne_bf16(float f) {
    uint32_t x = __float_as_uint(f);
    return (x + 0x7fffu + ((x >> 16) & 1u)) >> 16;
}
__device__ __forceinline__ float bf16lo(uint32_t u) { return __uint_as_float(u << 16); }
__device__ __forceinline__ float bf16hi(uint32_t u) { return __uint_as_float(u & 0xffff0000u); }

// lane i += lane (i^8)  within each 16-lane row, pure VALU (DPP row_ror:8),
// replacing one ds_bpermute level of the old shfl_xor reduce.
__device__ __forceinline__ float dpp_xor8_add(float x) {
    int y = __builtin_amdgcn_update_dpp(0, __float_as_int(x), 0x128, 0xF, 0xF, true);
    return x + __int_as_float(y);
}

// Kernel 1: XWh[node] = bf16( X @ W )  via mfma_f32_16x16x32_bf16.
// Linearity: sum_j X[j] @ W == sum_j (X@W)[j] -- dense GEMM hoisted BEFORE
// the aggregation. Traffic identical to a pure cast kernel.
__global__ __launch_bounds__(256) void xw_gemm_kernel(
    const float* __restrict__ X, const float* __restrict__ W,
    uint32_t* __restrict__ XWh, int n_nodes)
{
    const int lane = threadIdx.x & 63;
    const int n = lane & 15;
    const int q = lane >> 4;

    // A-frag (W^T): A[m = c*16 + n][k = kb*32 + q*8 + j] = W[k*64 + c*16 + n]
    s16x8 Af[4][2];
#pragma unroll
    for (int c = 0; c < 4; ++c)
#pragma unroll
        for (int kb = 0; kb < 2; ++kb) {
            s16x8 af;
#pragma unroll
            for (int j = 0; j < 8; ++j) {
                const int k = kb * 32 + q * 8 + j;
                af[j] = (short)rne_bf16(W[k * D + c * 16 + n]);
            }
            Af[c][kb] = af;
        }

    const int n_tiles = (n_nodes + 15) / 16;
    const int gwave = (int)((blockIdx.x * blockDim.x + threadIdx.x) >> 6);
    const int nwaves = (int)((gridDim.x * blockDim.x) >> 6);

    for (int t = gwave; t < n_tiles; t += nwaves) {
        const int m0 = t * 16;
        int arow = m0 + n;
        if (arow >= n_nodes) arow = n_nodes - 1;  // clamp (tail tile)
        const float* xp = X + (size_t)arow * D;

        // B-frag: B[k = kb*32 + q*8 + j][n] = X[node n][k]
        s16x8 Bf[2];
#pragma unroll
        for (int kb = 0; kb < 2; ++kb) {
            const f32x4 x0 = __builtin_nontemporal_load((const f32x4*)(xp + kb * 32 + q * 8));
            const f32x4 x1 = __builtin_nontemporal_load((const f32x4*)(xp + kb * 32 + q * 8 + 4));
            s16x8 b;
            b[0] = (short)rne_bf16(x0.x); b[1] = (short)rne_bf16(x0.y);
            b[2] = (short)rne_bf16(x0.z); b[3] = (short)rne_bf16(x0.w);
            b[4] = (short)rne_bf16(x1.x); b[5] = (short)rne_bf16(x1.y);
            b[6] = (short)rne_bf16(x1.z); b[7] = (short)rne_bf16(x1.w);
            Bf[kb] = b;
        }

        const bool live = (m0 + n) < n_nodes;
#pragma unroll
        for (int c = 0; c < 4; ++c) {
            f32x4 z = {0.f, 0.f, 0.f, 0.f};
            z = __builtin_amdgcn_mfma_f32_16x16x32_bf16(Af[c][0], Bf[0], z, 0, 0, 0);
            z = __builtin_amdgcn_mfma_f32_16x16x32_bf16(Af[c][1], Bf[1], z, 0, 0, 0);
            if (live) {
                // lane holds features c*16 + q*4 + {0..3} of node m0+n
                uint2 o;
                o.x = rne_bf16(z[0]) | (rne_bf16(z[1]) << 16);
                o.y = rne_bf16(z[2]) | (rne_bf16(z[3]) << 16);
                *(uint2*)(XWh + (size_t)(m0 + n) * 32 + c * 8 + q * 2) = o;
            }
        }
    }
}

// Kernel 2: out[r] = fp32( sum_{e in row r} XWh[ci[e]] ).
// PERSISTENT waves, grid-strided rows, 2-stage row pipeline.
//
// R5 post-mortem: three different per-wave schedules all land at ~45us ->
// the wall is invariant machinery, suspects: (a) 25k one-shot workgroups
// (launch/drain ~4.4cyc/WG), (b) per-row reduce on the LDS pipe (24
// ds_bpermute x 100k rows ~ 20us of per-CU LDS time). This kernel removes
// both: ~12k persistent waves each own ~8 rows; while row r's gathers are
// in flight, row r+stride's rp/ci loads are issued (pipeline keeps the
// miss queue full across rows); reduce level 1 moved to DPP (VALU).
// o = lane>>3 (edge slot 0..7), p = lane&7 (feature octet, 16B per lane).
__global__ __launch_bounds__(256) void gather_pers_kernel(
    const uint32_t* __restrict__ XWh, const int* __restrict__ rp,
    const int* __restrict__ ci, float* __restrict__ out, int n_nodes)
{
    const int lane = threadIdx.x & 63;
    const int o = lane >> 3;
    const int p = lane & 7;
    const int gw = (int)((blockIdx.x * blockDim.x + threadIdx.x) >> 6);
    const int nw = (int)((gridDim.x * blockDim.x) >> 6);

    int row = __builtin_amdgcn_readfirstlane(gw);  // wave-uniform -> SGPR
    if (row >= n_nodes) return;

    // Prologue: rp (s_load) + ci chunk-index loads for the first row.
    int e0 = rp[row];
    int e1 = rp[row + 1];
    int idx[8];
    bool v[8];
    {
        const int rem = e1 - e0;
#pragma unroll
        for (int t = 0; t < 8; ++t) {
            v[t] = (t * 8 + o) < rem;
            if (v[t]) idx[t] = ci[e0 + t * 8 + o];
        }
    }

    while (true) {
        const int nrow = row + nw;
        const bool have_next = nrow < n_nodes;  // wave-uniform

        // Stage 1: issue ALL gathers for the current row (indices ready).
        u32x4 u[8];
#pragma unroll
        for (int t = 0; t < 8; ++t)
            if (v[t]) u[t] = *(const u32x4*)(XWh + (size_t)idx[t] * 32 + p * 4);

        // Stage 2: prefetch next row's rp + ci -- independent of u[], so it
        // issues while the gathers are in flight.
        int ne0 = 0, ne1 = 0;
        int nidx[8];
        bool nv[8];
#pragma unroll
        for (int t = 0; t < 8; ++t) nv[t] = false;
        if (have_next) {
            ne0 = rp[nrow];
            ne1 = rp[nrow + 1];
            const int nrem = ne1 - ne0;
#pragma unroll
            for (int t = 0; t < 8; ++t) {
                nv[t] = (t * 8 + o) < nrem;
                if (nv[t]) nidx[t] = ci[ne0 + t * 8 + o];
            }
        }

        // Unpack + accumulate current row (vmcnt waits happen per-u here).
        float acc[8] = {0, 0, 0, 0, 0, 0, 0, 0};
#pragma unroll
        for (int t = 0; t < 8; ++t) {
            if (v[t]) {
#pragma unroll
                for (int k = 0; k < 4; ++k) {
                    acc[2 * k]     += bf16lo(u[t][k]);
                    acc[2 * k + 1] += bf16hi(u[t][k]);
                }
            }
        }

        // Rare slow path: rows with degree > 64 (P ~ 2% at deg~Exp(16)).
        for (int e = e0 + 64; e < e1; e += 64) {
            const int rem2 = e1 - e;
            int idx2[8];
            bool v2[8];
#pragma unroll
            for (int t = 0; t < 8; ++t) {
                v2[t] = (t * 8 + o) < rem2;
                if (v2[t]) idx2[t] = ci[e + t * 8 + o];
            }
            u32x4 u2[8];
#pragma unroll
            for (int t = 0; t < 8; ++t)
                if (v2[t]) u2[t] = *(const u32x4*)(XWh + (size_t)idx2[t] * 32 + p * 4);
#pragma unroll
            for (int t = 0; t < 8; ++t) {
                if (v2[t]) {
#pragma unroll
                    for (int k = 0; k < 4; ++k) {
                        acc[2 * k]     += bf16lo(u2[t][k]);
                        acc[2 * k + 1] += bf16hi(u2[t][k]);
                    }
                }
            }
        }

        // Reduce across the 8 edge slots (lane bits 3..5):
        // level ^8 on the VALU via DPP, levels ^16/^32 via shfl (ds pipe).
#pragma unroll
        for (int j = 0; j < 8; ++j) {
            float vv = dpp_xor8_add(acc[j]);
            vv += __shfl_xor(vv, 16, 64);
            vv += __shfl_xor(vv, 32, 64);
            acc[j] = vv;
        }
        if (lane < 8) {
            // lane p holds features p*8 .. p*8+7 of this row, fp32
            f32x4 w0 = {acc[0], acc[1], acc[2], acc[3]};
            f32x4 w1 = {acc[4], acc[5], acc[6], acc[7]};
            *(f32x4*)(out + (size_t)row * D + p * 8)     = w0;
            *(f32x4*)(out + (size_t)row * D + p * 8 + 4) = w1;
        }

        if (!have_next) break;
        row = nrow;
        e0 = ne0;
        e1 = ne1;
#pragma unroll
        for (int t = 0; t < 8; ++t) {
            v[t] = nv[t];
            idx[t] = nidx[t];
        }
    }
}

// Fallback if ws can't hold XWh: fused per-row aggregate + shfl GEMM.
__global__ __launch_bounds__(256) void fused_kernel(
    const float* __restrict__ X, const float* __restrict__ W,
    const int* __restrict__ rp, const int* __restrict__ ci,
    float* __restrict__ out, int n_nodes)
{
    __shared__ float Wl[D * D];
    for (int i = threadIdx.x; i < D * D; i += 256) Wl[i] = W[i];
    __syncthreads();

    const int lane = threadIdx.x & 63;
    const int gwave = (int)((blockIdx.x * blockDim.x + threadIdx.x) >> 6);
    const int nwaves = (int)((gridDim.x * blockDim.x) >> 6);

    for (int row = gwave; row < n_nodes; row += nwaves) {
        int e0 = rp[row];
        int e1 = rp[row + 1];
        float acc = 0.f;
        for (int e = e0; e < e1; ++e) acc += X[ci[e] * D + lane];
        float sum = 0.f;
#pragma unroll
        for (int d = 0; d < D; ++d) {
            float a = __shfl(acc, d, 64);
            sum += a * Wl[d * D + lane];
        }
        out[row * D + lane] = sum;
    }
}

extern "C" void kernel_launch(void* const* d_in, const int* in_sizes, int n_in,
                              void* d_out, int out_size, void* d_ws, size_t ws_size,
                              hipStream_t stream)
{
    const float* X  = (const float*)d_in[0];   // [n, 64]
    const float* W  = (const float*)d_in[1];   // [64, 64]
    const int*   rp = (const int*)d_in[2];     // [n+1]
    const int*   ci = (const int*)d_in[3];     // [n_edges]
    float* out = (float*)d_out;

    const int n_nodes = in_sizes[2] - 1;
    const size_t row_bytes = 32 * sizeof(uint32_t);       // 128 B bf16 row
    const size_t need = (size_t)n_nodes * row_bytes;      // XWh only

    if (ws_size >= need) {
        uint32_t* XWh = (uint32_t*)d_ws;

        // K1: XWh = bf16(X @ W). ~1.5 tiles/wave; W-frag setup amortized.
        xw_gemm_kernel<<<1024, 256, 0, stream>>>(X, W, XWh, n_nodes);

        // K2: persistent waves, ~8 rows each, 2-stage row pipeline.
        gather_pers_kernel<<<3072, 256, 0, stream>>>(XWh, rp, ci, out, n_nodes);
    } else {
        fused_kernel<<<2048, 256, 0, stream>>>(X, W, rp, ci, out, n_nodes);
    }
}

// Round 7
// 154.317 us; speedup vs baseline: 1.0560x; 1.0560x over previous
//
#include <hip/hip_runtime.h>
#include <cstdint>
#include <cstddef>

#define D 64

typedef float    f32x4 __attribute__((ext_vector_type(4)));
typedef short    s16x8 __attribute__((ext_vector_type(8)));
typedef uint32_t u32x4 __attribute__((ext_vector_type(4)));

// round-to-nearest-even fp32 -> bf16 (bits in low 16)
__device__ __forceinline__ uint32_t rne_bf16(float f) {
    uint32_t x = __float_as_uint(f);
    return (x + 0x7fffu + ((x >> 16) & 1u)) >> 16;
}

// Kernel 1: XWh[node] = bf16( X @ W )  via mfma_f32_16x16x32_bf16.
// Linearity: sum_j X[j] @ W == sum_j (X@W)[j] -- dense GEMM hoisted BEFORE
// the aggregation. Traffic identical to a pure cast kernel.
__global__ __launch_bounds__(256) void xw_gemm_kernel(
    const float* __restrict__ X, const float* __restrict__ W,
    uint32_t* __restrict__ XWh, int n_nodes)
{
    const int lane = threadIdx.x & 63;
    const int n = lane & 15;
    const int q = lane >> 4;

    // A-frag (W^T): A[m = c*16 + n][k = kb*32 + q*8 + j] = W[k*64 + c*16 + n]
    s16x8 Af[4][2];
#pragma unroll
    for (int c = 0; c < 4; ++c)
#pragma unroll
        for (int kb = 0; kb < 2; ++kb) {
            s16x8 af;
#pragma unroll
            for (int j = 0; j < 8; ++j) {
                const int k = kb * 32 + q * 8 + j;
                af[j] = (short)rne_bf16(W[k * D + c * 16 + n]);
            }
            Af[c][kb] = af;
        }

    const int n_tiles = (n_nodes + 15) / 16;
    const int gwave = (int)((blockIdx.x * blockDim.x + threadIdx.x) >> 6);
    const int nwaves = (int)((gridDim.x * blockDim.x) >> 6);

    for (int t = gwave; t < n_tiles; t += nwaves) {
        const int m0 = t * 16;
        int arow = m0 + n;
        if (arow >= n_nodes) arow = n_nodes - 1;  // clamp (tail tile)
        const float* xp = X + (size_t)arow * D;

        // B-frag: B[k = kb*32 + q*8 + j][n] = X[node n][k]
        s16x8 Bf[2];
#pragma unroll
        for (int kb = 0; kb < 2; ++kb) {
            const f32x4 x0 = __builtin_nontemporal_load((const f32x4*)(xp + kb * 32 + q * 8));
            const f32x4 x1 = __builtin_nontemporal_load((const f32x4*)(xp + kb * 32 + q * 8 + 4));
            s16x8 b;
            b[0] = (short)rne_bf16(x0.x); b[1] = (short)rne_bf16(x0.y);
            b[2] = (short)rne_bf16(x0.z); b[3] = (short)rne_bf16(x0.w);
            b[4] = (short)rne_bf16(x1.x); b[5] = (short)rne_bf16(x1.y);
            b[6] = (short)rne_bf16(x1.z); b[7] = (short)rne_bf16(x1.w);
            Bf[kb] = b;
        }

        const bool live = (m0 + n) < n_nodes;
#pragma unroll
        for (int c = 0; c < 4; ++c) {
            f32x4 z = {0.f, 0.f, 0.f, 0.f};
            z = __builtin_amdgcn_mfma_f32_16x16x32_bf16(Af[c][0], Bf[0], z, 0, 0, 0);
            z = __builtin_amdgcn_mfma_f32_16x16x32_bf16(Af[c][1], Bf[1], z, 0, 0, 0);
            if (live) {
                // lane holds features c*16 + q*4 + {0..3} of node m0+n
                uint2 o;
                o.x = rne_bf16(z[0]) | (rne_bf16(z[1]) << 16);
                o.y = rne_bf16(z[2]) | (rne_bf16(z[3]) << 16);
                *(uint2*)(XWh + (size_t)(m0 + n) * 32 + c * 8 + q * 2) = o;
            }
        }
    }
}

// Kernel 2: out[r] = fp32( sum_{e in row r} XWh[ci[e]] ).
// ONE row per wave (100k waves -- proven-best TLP), LANE = FEATURE.
//
// R6 post-mortem: TLP is the engine (100k->25k->12k waves gave 45.6->50.4->
// 64.7us); the remaining suspect is per-wave overhead sharing the pipes.
// This wave is stripped to the minimum:
//   - row is wave-uniform -> rp/ci reads are scalar/broadcast (1 line each),
//     gather base address computed on the SCALAR pipe; the gather is
//     global_load_dword with SGPR base + tiny VGPR offset.
//   - lane owns feature f = lane: reads dword f>>1 of the 128B row, selects
//     lo/hi bf16 by lane parity (v_lshlrev + v_and, 2 VALU) + 1 v_add.
//   - NO vector idx loads, NO predication, NO cross-lane reduce, NO repack.
//   - one VMEM instr = one edge = exactly one 128B line; 8 independent
//     edges per batch keep the miss queue full.
// Per edge: 1 VMEM + 3 VALU + ~3 SALU. Store: 64 lanes x 4B contiguous.
__global__ __launch_bounds__(256) void gather_feat_kernel(
    const uint32_t* __restrict__ XWh, const int* __restrict__ rp,
    const int* __restrict__ ci, float* __restrict__ out, int n_nodes)
{
    const int lane = threadIdx.x & 63;
    const int gw = (int)((blockIdx.x * blockDim.x + threadIdx.x) >> 6);
    const int row = __builtin_amdgcn_readfirstlane(gw);  // wave-uniform
    if (row >= n_nodes) return;

    const int e0 = rp[row];      // uniform -> scalar path
    const int e1 = rp[row + 1];

    const int dwoff = lane >> 1;               // dword 0..31 within the row
    const uint32_t sh = (lane & 1) ? 0u : 16u; // even lane: lo half -> <<16

    float acc = 0.f;

    int e = e0;
    // batches of 8 edges: 8 scalar indices, then 8 independent 1-line gathers
    for (; e + 8 <= e1; e += 8) {
        uint32_t u[8];
#pragma unroll
        for (int t = 0; t < 8; ++t) {
            const int idx = __builtin_amdgcn_readfirstlane(ci[e + t]);
            u[t] = XWh[(size_t)idx * 32 + dwoff];
        }
#pragma unroll
        for (int t = 0; t < 8; ++t)
            acc += __uint_as_float((u[t] << sh) & 0xffff0000u);
    }
    // remainder (< 8 edges), uniform trip count -> scalar branches
    for (; e < e1; ++e) {
        const int idx = __builtin_amdgcn_readfirstlane(ci[e]);
        const uint32_t u = XWh[(size_t)idx * 32 + dwoff];
        acc += __uint_as_float((u << sh) & 0xffff0000u);
    }

    out[(size_t)row * D + lane] = acc;  // 256B contiguous per wave
}

// Fallback if ws can't hold XWh: fused per-row aggregate + shfl GEMM.
__global__ __launch_bounds__(256) void fused_kernel(
    const float* __restrict__ X, const float* __restrict__ W,
    const int* __restrict__ rp, const int* __restrict__ ci,
    float* __restrict__ out, int n_nodes)
{
    __shared__ float Wl[D * D];
    for (int i = threadIdx.x; i < D * D; i += 256) Wl[i] = W[i];
    __syncthreads();

    const int lane = threadIdx.x & 63;
    const int gwave = (int)((blockIdx.x * blockDim.x + threadIdx.x) >> 6);
    const int nwaves = (int)((gridDim.x * blockDim.x) >> 6);

    for (int row = gwave; row < n_nodes; row += nwaves) {
        int e0 = rp[row];
        int e1 = rp[row + 1];
        float acc = 0.f;
        for (int e = e0; e < e1; ++e) acc += X[ci[e] * D + lane];
        float sum = 0.f;
#pragma unroll
        for (int d = 0; d < D; ++d) {
            float a = __shfl(acc, d, 64);
            sum += a * Wl[d * D + lane];
        }
        out[row * D + lane] = sum;
    }
}

extern "C" void kernel_launch(void* const* d_in, const int* in_sizes, int n_in,
                              void* d_out, int out_size, void* d_ws, size_t ws_size,
                              hipStream_t stream)
{
    const float* X  = (const float*)d_in[0];   // [n, 64]
    const float* W  = (const float*)d_in[1];   // [64, 64]
    const int*   rp = (const int*)d_in[2];     // [n+1]
    const int*   ci = (const int*)d_in[3];     // [n_edges]
    float* out = (float*)d_out;

    const int n_nodes = in_sizes[2] - 1;
    const size_t row_bytes = 32 * sizeof(uint32_t);       // 128 B bf16 row
    const size_t need = (size_t)n_nodes * row_bytes;      // XWh only

    if (ws_size >= need) {
        uint32_t* XWh = (uint32_t*)d_ws;

        // K1: XWh = bf16(X @ W). ~1.5 tiles/wave; W-frag setup amortized.
        xw_gemm_kernel<<<1024, 256, 0, stream>>>(X, W, XWh, n_nodes);

        // K2: gather-aggregate rows of XWh -> fp32 out. 1 row/wave,
        // lane=feature, minimal-overhead wave.
        const int gather_blocks = (n_nodes + 3) / 4;  // 4 waves/block
        gather_feat_kernel<<<gather_blocks, 256, 0, stream>>>(XWh, rp, ci, out, n_nodes);
    } else {
        fused_kernel<<<2048, 256, 0, stream>>>(X, W, rp, ci, out, n_nodes);
    }
}

// Round 8
// 141.275 us; speedup vs baseline: 1.1535x; 1.0923x over previous
//
#include <hip/hip_runtime.h>
#include <cstdint>
#include <cstddef>

#define D 64

typedef float    f32x4 __attribute__((ext_vector_type(4)));
typedef short    s16x8 __attribute__((ext_vector_type(8)));
typedef uint32_t u32x4 __attribute__((ext_vector_type(4)));

// round-to-nearest-even fp32 -> bf16 (bits in low 16)
__device__ __forceinline__ uint32_t rne_bf16(float f) {
    uint32_t x = __float_as_uint(f);
    return (x + 0x7fffu + ((x >> 16) & 1u)) >> 16;
}
__device__ __forceinline__ float bf16lo(uint32_t u) { return __uint_as_float(u << 16); }
__device__ __forceinline__ float bf16hi(uint32_t u) { return __uint_as_float(u & 0xffff0000u); }

// Kernel 1: XWh[node] = bf16( X @ W )  via mfma_f32_16x16x32_bf16.
// Linearity: sum_j X[j] @ W == sum_j (X@W)[j] -- dense GEMM hoisted BEFORE
// the aggregation. Traffic identical to a pure cast kernel.
__global__ __launch_bounds__(256) void xw_gemm_kernel(
    const float* __restrict__ X, const float* __restrict__ W,
    uint32_t* __restrict__ XWh, int n_nodes)
{
    const int lane = threadIdx.x & 63;
    const int n = lane & 15;
    const int q = lane >> 4;

    // A-frag (W^T): A[m = c*16 + n][k = kb*32 + q*8 + j] = W[k*64 + c*16 + n]
    s16x8 Af[4][2];
#pragma unroll
    for (int c = 0; c < 4; ++c)
#pragma unroll
        for (int kb = 0; kb < 2; ++kb) {
            s16x8 af;
#pragma unroll
            for (int j = 0; j < 8; ++j) {
                const int k = kb * 32 + q * 8 + j;
                af[j] = (short)rne_bf16(W[k * D + c * 16 + n]);
            }
            Af[c][kb] = af;
        }

    const int n_tiles = (n_nodes + 15) / 16;
    const int gwave = (int)((blockIdx.x * blockDim.x + threadIdx.x) >> 6);
    const int nwaves = (int)((gridDim.x * blockDim.x) >> 6);

    for (int t = gwave; t < n_tiles; t += nwaves) {
        const int m0 = t * 16;
        int arow = m0 + n;
        if (arow >= n_nodes) arow = n_nodes - 1;  // clamp (tail tile)
        const float* xp = X + (size_t)arow * D;

        // B-frag: B[k = kb*32 + q*8 + j][n] = X[node n][k]
        s16x8 Bf[2];
#pragma unroll
        for (int kb = 0; kb < 2; ++kb) {
            const f32x4 x0 = __builtin_nontemporal_load((const f32x4*)(xp + kb * 32 + q * 8));
            const f32x4 x1 = __builtin_nontemporal_load((const f32x4*)(xp + kb * 32 + q * 8 + 4));
            s16x8 b;
            b[0] = (short)rne_bf16(x0.x); b[1] = (short)rne_bf16(x0.y);
            b[2] = (short)rne_bf16(x0.z); b[3] = (short)rne_bf16(x0.w);
            b[4] = (short)rne_bf16(x1.x); b[5] = (short)rne_bf16(x1.y);
            b[6] = (short)rne_bf16(x1.z); b[7] = (short)rne_bf16(x1.w);
            Bf[kb] = b;
        }

        const bool live = (m0 + n) < n_nodes;
#pragma unroll
        for (int c = 0; c < 4; ++c) {
            f32x4 z = {0.f, 0.f, 0.f, 0.f};
            z = __builtin_amdgcn_mfma_f32_16x16x32_bf16(Af[c][0], Bf[0], z, 0, 0, 0);
            z = __builtin_amdgcn_mfma_f32_16x16x32_bf16(Af[c][1], Bf[1], z, 0, 0, 0);
            if (live) {
                // lane holds features c*16 + q*4 + {0..3} of node m0+n
                uint2 o;
                o.x = rne_bf16(z[0]) | (rne_bf16(z[1]) << 16);
                o.y = rne_bf16(z[2]) | (rne_bf16(z[3]) << 16);
                *(uint2*)(XWh + (size_t)(m0 + n) * 32 + c * 8 + q * 2) = o;
            }
        }
    }
}

// Kernel 2: out[r] = fp32( sum_{e in row r} XWh[ci[e]] ).
// ONE row per wave. o = lane>>3 (edge slot 0..7), p = lane&7 (feature octet,
// u32x4 = 8 bf16 = full 128B row across 8 lanes). 8 edges per load instr.
// Main iter = 32 edges: 4 independent idx loads then 4 independent gathers
// -> up to 8 loads in flight per wave.
//
// MEASURED-BEST schedule (R3: 45.8us; R5 variant 45.6us). Five alternative
// schedules (4-row phased, single-shot, persistent pipelined, lane=feature)
// all landed at >= this time: the kernel sits at the per-CU outstanding-miss
// x latency service floor for 1.6M random 128B lines (~48 MSHR/CU x ~400ns
// -> ~30 lines/ns -> ~50us). Schedule changes cannot move it.
__global__ __launch_bounds__(256) void gather_out_kernel(
    const uint32_t* __restrict__ XWh, const int* __restrict__ rp,
    const int* __restrict__ ci, float* __restrict__ out, int n_nodes)
{
    const int lane = threadIdx.x & 63;
    const int o = lane >> 3;
    const int p = lane & 7;
    const int row = (int)((blockIdx.x * blockDim.x + threadIdx.x) >> 6);
    if (row >= n_nodes) return;

    const int e0 = rp[row];
    const int e1 = rp[row + 1];

    float a[8] = {0,0,0,0,0,0,0,0};
    float b[8] = {0,0,0,0,0,0,0,0};

    int e = e0;
    // main: 32 edges per iteration, all loads independent
    for (; e + 32 <= e1; e += 32) {
        const int i0 = ci[e      + o];
        const int i1 = ci[e +  8 + o];
        const int i2 = ci[e + 16 + o];
        const int i3 = ci[e + 24 + o];
        const u32x4 u0 = *(const u32x4*)(XWh + (size_t)i0 * 32 + p * 4);
        const u32x4 u1 = *(const u32x4*)(XWh + (size_t)i1 * 32 + p * 4);
        const u32x4 u2 = *(const u32x4*)(XWh + (size_t)i2 * 32 + p * 4);
        const u32x4 u3 = *(const u32x4*)(XWh + (size_t)i3 * 32 + p * 4);
#pragma unroll
        for (int k = 0; k < 4; ++k) {
            a[2*k] += bf16lo(u0[k]); a[2*k+1] += bf16hi(u0[k]);
            b[2*k] += bf16lo(u1[k]); b[2*k+1] += bf16hi(u1[k]);
            a[2*k] += bf16lo(u2[k]); a[2*k+1] += bf16hi(u2[k]);
            b[2*k] += bf16lo(u3[k]); b[2*k+1] += bf16hi(u3[k]);
        }
    }
    // 16-edge step
    if (e + 16 <= e1) {
        const int i0 = ci[e     + o];
        const int i1 = ci[e + 8 + o];
        const u32x4 u0 = *(const u32x4*)(XWh + (size_t)i0 * 32 + p * 4);
        const u32x4 u1 = *(const u32x4*)(XWh + (size_t)i1 * 32 + p * 4);
#pragma unroll
        for (int k = 0; k < 4; ++k) {
            a[2*k] += bf16lo(u0[k]); a[2*k+1] += bf16hi(u0[k]);
            b[2*k] += bf16lo(u1[k]); b[2*k+1] += bf16hi(u1[k]);
        }
        e += 16;
    }
    // 8-edge step
    if (e + 8 <= e1) {
        const int i0 = ci[e + o];
        const u32x4 u0 = *(const u32x4*)(XWh + (size_t)i0 * 32 + p * 4);
#pragma unroll
        for (int k = 0; k < 4; ++k) {
            a[2*k] += bf16lo(u0[k]); a[2*k+1] += bf16hi(u0[k]);
        }
        e += 8;
    }
    // final 0..7 edges, predicated over o
    if (o < e1 - e) {
        const int i0 = ci[e + o];
        const u32x4 u0 = *(const u32x4*)(XWh + (size_t)i0 * 32 + p * 4);
#pragma unroll
        for (int k = 0; k < 4; ++k) {
            b[2*k] += bf16lo(u0[k]); b[2*k+1] += bf16hi(u0[k]);
        }
    }

    // reduce across the 8 edge slots (bits 3..5 of lane); lanes 0..7 get sums
#pragma unroll
    for (int j = 0; j < 8; ++j) {
        float v = a[j] + b[j];
        v += __shfl_xor(v, 8, 64);
        v += __shfl_xor(v, 16, 64);
        v += __shfl_xor(v, 32, 64);
        a[j] = v;
    }
    if (lane < 8) {
        // lane p holds features p*8 .. p*8+7 of this row, fp32
        f32x4 w0 = {a[0], a[1], a[2], a[3]};
        f32x4 w1 = {a[4], a[5], a[6], a[7]};
        *(f32x4*)(out + (size_t)row * D + p * 8)     = w0;
        *(f32x4*)(out + (size_t)row * D + p * 8 + 4) = w1;
    }
}

// Fallback if ws can't hold XWh: fused per-row aggregate + shfl GEMM.
__global__ __launch_bounds__(256) void fused_kernel(
    const float* __restrict__ X, const float* __restrict__ W,
    const int* __restrict__ rp, const int* __restrict__ ci,
    float* __restrict__ out, int n_nodes)
{
    __shared__ float Wl[D * D];
    for (int i = threadIdx.x; i < D * D; i += 256) Wl[i] = W[i];
    __syncthreads();

    const int lane = threadIdx.x & 63;
    const int gwave = (int)((blockIdx.x * blockDim.x + threadIdx.x) >> 6);
    const int nwaves = (int)((gridDim.x * blockDim.x) >> 6);

    for (int row = gwave; row < n_nodes; row += nwaves) {
        int e0 = rp[row];
        int e1 = rp[row + 1];
        float acc = 0.f;
        for (int e = e0; e < e1; ++e) acc += X[ci[e] * D + lane];
        float sum = 0.f;
#pragma unroll
        for (int d = 0; d < D; ++d) {
            float a = __shfl(acc, d, 64);
            sum += a * Wl[d * D + lane];
        }
        out[row * D + lane] = sum;
    }
}

extern "C" void kernel_launch(void* const* d_in, const int* in_sizes, int n_in,
                              void* d_out, int out_size, void* d_ws, size_t ws_size,
                              hipStream_t stream)
{
    const float* X  = (const float*)d_in[0];   // [n, 64]
    const float* W  = (const float*)d_in[1];   // [64, 64]
    const int*   rp = (const int*)d_in[2];     // [n+1]
    const int*   ci = (const int*)d_in[3];     // [n_edges]
    float* out = (float*)d_out;

    const int n_nodes = in_sizes[2] - 1;
    const size_t row_bytes = 32 * sizeof(uint32_t);       // 128 B bf16 row
    const size_t need = (size_t)n_nodes * row_bytes;      // XWh only

    if (ws_size >= need) {
        uint32_t* XWh = (uint32_t*)d_ws;

        // K1: XWh = bf16(X @ W). ~1.5 tiles/wave; W-frag setup amortized.
        xw_gemm_kernel<<<1024, 256, 0, stream>>>(X, W, XWh, n_nodes);

        // K2: gather-aggregate rows of XWh -> fp32 out. 1 row/wave.
        const int gather_blocks = (n_nodes + 3) / 4;  // 4 waves/block
        gather_out_kernel<<<gather_blocks, 256, 0, stream>>>(XWh, rp, ci, out, n_nodes);
    } else {
        fused_kernel<<<2048, 256, 0, stream>>>(X, W, rp, ci, out, n_nodes);
    }
}